// Round 4
// baseline (513.270 us; speedup 1.0000x reference)
//
#include <hip/hip_runtime.h>

#define BB 128
#define TE 2048
#define UU 256
#define IN_DIM 256
#define MC 64
#define TCH (TE / MC)  // 32

typedef float f32x4 __attribute__((ext_vector_type(4)));
typedef short bf16x8 __attribute__((ext_vector_type(8)));
typedef unsigned short u16x4 __attribute__((ext_vector_type(4)));

__device__ __forceinline__ unsigned short f2bf(float f) {
  unsigned u = __float_as_uint(f);
  u += 0x7fffu + ((u >> 16) & 1u);  // RNE
  return (unsigned short)(u >> 16);
}
__device__ __forceinline__ float bf2f(unsigned short s) {
  return __uint_as_float(((unsigned)s) << 16);
}
__device__ __forceinline__ float fast_tanh(float x) {
  float e = __expf(2.f * x);
  return 1.f - 2.f / (e + 1.f);
}
__device__ __forceinline__ float fast_sigmoid(float x) {
  return 1.f / (1.f + __expf(-x));
}

// ---------------- prep: addvec = h_tm@W_a + b_a ; UaT = bf16(U_a)^T ----------------
__global__ __launch_bounds__(256) void prep_kernel(
    const float* __restrict__ h_tm, const float* __restrict__ W_a,
    const float* __restrict__ b_a, const float* __restrict__ U_a,
    float* __restrict__ addvec, unsigned short* __restrict__ UaT) {
  int t = threadIdx.x;
  if (blockIdx.x < BB) {
    int bi = blockIdx.x;
    __shared__ float hL[UU];
    hL[t] = h_tm[bi * UU + t];
    __syncthreads();
    float s = b_a[t];
    for (int e = 0; e < UU; ++e) s += hL[e] * W_a[e * UU + t];
    addvec[bi * UU + t] = s;
  } else {
    int idx = (blockIdx.x - BB) * 256 + t;  // 0..16383, covers 256x256/4
    int n = idx >> 6;
    int k0 = (idx & 63) << 2;
    u16x4 pkt;
    pkt.x = f2bf(U_a[(k0 + 0) * UU + n]);
    pkt.y = f2bf(U_a[(k0 + 1) * UU + n]);
    pkt.z = f2bf(U_a[(k0 + 2) * UU + n]);
    pkt.w = f2bf(U_a[(k0 + 3) * UU + n]);
    *(u16x4*)(UaT + n * UU + k0) = pkt;  // UaT[n][k] = U_a[k][n]
  }
}

// ---------------- main: per (batch, 64-timestep chunk): et, exp, partial num/den -----
__global__ __launch_bounds__(256) void attn_main(
    const float* __restrict__ x_seq, const float* __restrict__ V_a,
    const unsigned short* __restrict__ UaT, const float* __restrict__ addvec,
    float* __restrict__ numw, float* __restrict__ denw) {
  __shared__ __align__(16) unsigned char Xb[MC * 512];  // 64 rows x 256 bf16, XOR-swizzled
  __shared__ float avL[UU];
  __shared__ float vaL[UU];
  __shared__ float wsum[4][MC];
  __shared__ float eL[MC];

  const int tid = threadIdx.x;
  const int bi = blockIdx.x / TCH;
  const int c = blockIdx.x % TCH;

  const float* xc = x_seq + (size_t)(bi * TE + c * MC) * UU;

  // stage X chunk -> LDS bf16, swizzle byte ^= (row&7)<<4  (kills b128 bank conflicts)
#pragma unroll
  for (int i = 0; i < 16; ++i) {
    int f4 = i * 256 + tid;      // float4 index, 0..4095
    int m = f4 >> 6;             // row 0..63
    int k = (f4 & 63) << 2;      // col 0..252
    f32x4 v = *(const f32x4*)(xc + (size_t)f4 * 4);
    u16x4 pkt;
    pkt.x = f2bf(v.x);
    pkt.y = f2bf(v.y);
    pkt.z = f2bf(v.z);
    pkt.w = f2bf(v.w);
    int woff = m * 512 + ((k << 1) ^ ((m & 7) << 4));
    *(u16x4*)(Xb + woff) = pkt;
  }
  avL[tid] = addvec[bi * UU + tid];
  vaL[tid] = V_a[tid];
  __syncthreads();

  const int w = tid >> 6;
  const int l = tid & 63;
  const int lr = l & 15;
  const int lg = l >> 4;
  const int n0 = w * 64;  // wave's 64 output columns

  f32x4 acc[4][4];
#pragma unroll
  for (int mi = 0; mi < 4; ++mi)
#pragma unroll
    for (int ni = 0; ni < 4; ++ni) acc[mi][ni] = (f32x4)0.f;

#pragma unroll
  for (int ks = 0; ks < 8; ++ks) {
    bf16x8 a[4], b[4];
#pragma unroll
    for (int ni = 0; ni < 4; ++ni) {
      int n = n0 + ni * 16 + lr;
      b[ni] = *(const bf16x8*)(UaT + n * UU + ks * 32 + lg * 8);  // contiguous 16B, L2-hit
    }
#pragma unroll
    for (int mi = 0; mi < 4; ++mi) {
      int m = mi * 16 + lr;
      int off = m * 512 + ((ks * 64 + lg * 16) ^ ((m & 7) << 4));
      a[mi] = *(const bf16x8*)(Xb + off);  // ds_read_b128
    }
#pragma unroll
    for (int mi = 0; mi < 4; ++mi)
#pragma unroll
      for (int ni = 0; ni < 4; ++ni)
        acc[mi][ni] =
            __builtin_amdgcn_mfma_f32_16x16x32_bf16(a[mi], b[ni], acc[mi][ni], 0, 0, 0);
  }

  // epilogue: psum[mi][r] = sum over wave's 64 cols of tanh(S+av)*va
  float psum[4][4];
#pragma unroll
  for (int mi = 0; mi < 4; ++mi)
#pragma unroll
    for (int r = 0; r < 4; ++r) psum[mi][r] = 0.f;

#pragma unroll
  for (int ni = 0; ni < 4; ++ni) {
    int n = n0 + ni * 16 + lr;
    float av = avL[n];
    float va = vaL[n];
#pragma unroll
    for (int mi = 0; mi < 4; ++mi)
#pragma unroll
      for (int r = 0; r < 4; ++r)
        psum[mi][r] += fast_tanh(acc[mi][ni][r] + av) * va;
  }
  // reduce across the 16 lanes holding different cols (lane bits 0..3)
#pragma unroll
  for (int off = 1; off < 16; off <<= 1)
#pragma unroll
    for (int mi = 0; mi < 4; ++mi)
#pragma unroll
      for (int r = 0; r < 4; ++r) psum[mi][r] += __shfl_xor(psum[mi][r], off, 64);

  if (lr == 0) {
#pragma unroll
    for (int mi = 0; mi < 4; ++mi)
#pragma unroll
      for (int r = 0; r < 4; ++r) wsum[w][mi * 16 + lg * 4 + r] = psum[mi][r];  // row m
  }
  __syncthreads();

  if (tid < MC) {
    float et = wsum[0][tid] + wsum[1][tid] + wsum[2][tid] + wsum[3][tid];
    eL[tid] = __expf(et);  // unnormalized, matches reference
  }
  __syncthreads();

  if (tid == 0) {
    float d = 0.f;
    for (int m = 0; m < MC; ++m) d += eL[m];
    denw[bi * TCH + c] = d;
  }
  // partial num[n] = sum_m e[m] * X[m][n]
  float s = 0.f;
  const int sw_n = tid << 1;
#pragma unroll 8
  for (int m = 0; m < MC; ++m) {
    int off = m * 512 + (sw_n ^ ((m & 7) << 4));
    s += eL[m] * bf2f(*(const unsigned short*)(Xb + off));
  }
  numw[(bi * TCH + c) * UU + tid] = s;
}

// ---------------- finalize: reduce partials -> context -> gates -> ht ----------------
__global__ __launch_bounds__(256) void finalize_kernel(
    const float* __restrict__ inputs, const float* __restrict__ h_tm,
    const float* __restrict__ numw, const float* __restrict__ denw,
    const float* __restrict__ C_z, const float* __restrict__ W_z,
    const float* __restrict__ b_z, const float* __restrict__ C_r,
    const float* __restrict__ W_r, const float* __restrict__ b_r,
    const float* __restrict__ C_p, const float* __restrict__ U_p,
    const float* __restrict__ b_p, float* __restrict__ out) {
  int bi = blockIdx.x, t = threadIdx.x;
  __shared__ float hL[UU], ciL[IN_DIM + UU], rhL[UU];
  float ns = 0.f;
#pragma unroll 4
  for (int c = 0; c < TCH; ++c) ns += numw[(bi * TCH + c) * UU + t];
  float ds = 0.f;
  for (int c = 0; c < TCH; ++c) ds += denw[bi * TCH + c];
  ciL[IN_DIM + t] = ns / ds;          // context
  ciL[t] = inputs[bi * IN_DIM + t];   // inputs
  hL[t] = h_tm[bi * UU + t];
  __syncthreads();

  float z = b_z[t], r = b_r[t], p = b_p[t];
  for (int e = 0; e < UU; ++e) {
    float h = hL[e];
    z += h * W_z[e * UU + t];
    r += h * W_r[e * UU + t];
  }
  for (int e = 0; e < IN_DIM + UU; ++e) {
    float cv = ciL[e];
    z += cv * C_z[e * UU + t];
    r += cv * C_r[e * UU + t];
    p += cv * C_p[e * UU + t];
  }
  z = fast_sigmoid(z);
  r = fast_sigmoid(r);
  rhL[t] = r * hL[t];
  __syncthreads();
  for (int e = 0; e < UU; ++e) p += rhL[e] * U_p[e * UU + t];
  float th = fast_tanh(p);
  out[bi * UU + t] = (1.f - z) * hL[t] + z * th;
}

extern "C" void kernel_launch(void* const* d_in, const int* in_sizes, int n_in,
                              void* d_out, int out_size, void* d_ws, size_t ws_size,
                              hipStream_t stream) {
  const float* inputs = (const float*)d_in[0];
  const float* h_tm = (const float*)d_in[1];
  const float* x_seq = (const float*)d_in[2];
  const float* V_a = (const float*)d_in[3];
  const float* W_a = (const float*)d_in[4];
  const float* U_a = (const float*)d_in[5];
  const float* b_a = (const float*)d_in[6];
  const float* C_z = (const float*)d_in[7];
  const float* W_z = (const float*)d_in[8];
  const float* b_z = (const float*)d_in[9];
  const float* C_r = (const float*)d_in[10];
  const float* W_r = (const float*)d_in[11];
  const float* b_r = (const float*)d_in[12];
  const float* C_p = (const float*)d_in[13];
  const float* U_p = (const float*)d_in[14];
  const float* b_p = (const float*)d_in[15];

  // ws layout: UaT bf16 [256][256] (128KB) | addvec f32 [128][256] (128KB)
  //            | num f32 [128][32][256] (4MB) | den f32 [128][32] (16KB)
  unsigned short* UaT = (unsigned short*)d_ws;
  float* addvec = (float*)((char*)d_ws + 131072);
  float* numw = (float*)((char*)d_ws + 262144);
  float* denw = (float*)((char*)d_ws + 262144 + 4194304);
  float* out = (float*)d_out;

  prep_kernel<<<BB + 64, 256, 0, stream>>>(h_tm, W_a, b_a, U_a, addvec, UaT);
  attn_main<<<BB * TCH, 256, 0, stream>>>(x_seq, V_a, UaT, addvec, numw, denw);
  finalize_kernel<<<BB, 256, 0, stream>>>(inputs, h_tm, numw, denw, C_z, W_z, b_z, C_r,
                                          W_r, b_r, C_p, U_p, b_p, out);
}